// Round 1
// baseline (184.321 us; speedup 1.0000x reference)
//
#include <hip/hip_runtime.h>
#include <math.h>

// Problem constants (B=4, S=2048, E=1024, A=64)
#define BATCH 4
#define SLEN  2048
#define EMB   1024
#define AH    64

// ---------------------------------------------------------------------------
// Kernel 0: transpose Wk [64,1024] -> WkT [1024,64]
// ---------------------------------------------------------------------------
__global__ __launch_bounds__(256) void wk_transpose_kernel(const float* __restrict__ Wk,
                                                           float* __restrict__ WkT) {
  int gid = blockIdx.x * 256 + threadIdx.x;  // 65536 elements, grid=256
  int e = gid >> 6, a = gid & 63;
  WkT[gid] = Wk[(size_t)a * EMB + e];
}

// ---------------------------------------------------------------------------
// Kernel 1: Kmat[r][a] = sum_e emb[r][e] * Wk[a][e]   (r in [0,8192))
// Also writes KmatT[b][a][s] for transposed access in the flash kernel.
// Tile: 32 rows x 64 cols, 256 threads, 2x4 register tile, E-chunks of 64.
// ---------------------------------------------------------------------------
__global__ __launch_bounds__(256) void gemm_k_kernel(const float* __restrict__ emb,
                                                     const float* __restrict__ WkT,
                                                     float* __restrict__ Kmat,
                                                     float* __restrict__ KmatT) {
  __shared__ float At[64][34];  // At[e][r]  (transposed emb tile), stride 34: 4-way write ok
  __shared__ float Wt[64][68];  // Wt[e][a]  (natural from WkT), float4-friendly
  const int t = threadIdx.x, tx = t & 15, ty = t >> 4;
  const int row0 = blockIdx.x * 32;
  const int c4 = tx * 4;
  float acc[2][4] = {{0.f, 0.f, 0.f, 0.f}, {0.f, 0.f, 0.f, 0.f}};

  for (int ec = 0; ec < 16; ++ec) {
    // stage emb tile (32 rows x 64 e), transposed into At
    for (int p = 0; p < 2; ++p) {
      int r = ty + p * 16;
      float4 v = *(const float4*)&emb[(size_t)(row0 + r) * EMB + ec * 64 + c4];
      At[c4 + 0][r] = v.x; At[c4 + 1][r] = v.y; At[c4 + 2][r] = v.z; At[c4 + 3][r] = v.w;
    }
    // stage WkT tile (64 e x 64 a), natural
    for (int p = 0; p < 4; ++p) {
      int e = ty + p * 16;
      *(float4*)&Wt[e][c4] = *(const float4*)&WkT[(size_t)(ec * 64 + e) * 64 + c4];
    }
    __syncthreads();
#pragma unroll 8
    for (int e = 0; e < 64; ++e) {
      float2 av = *(const float2*)&At[e][ty * 2];
      float4 wv = *(const float4*)&Wt[e][tx * 4];
      acc[0][0] += av.x * wv.x; acc[0][1] += av.x * wv.y;
      acc[0][2] += av.x * wv.z; acc[0][3] += av.x * wv.w;
      acc[1][0] += av.y * wv.x; acc[1][1] += av.y * wv.y;
      acc[1][2] += av.y * wv.z; acc[1][3] += av.y * wv.w;
    }
    __syncthreads();
  }

  const int b = row0 >> 11, s0 = row0 & 2047;
  for (int rr = 0; rr < 2; ++rr) {
    int r = ty * 2 + rr;
    *(float4*)&Kmat[(size_t)(row0 + r) * AH + tx * 4] =
        make_float4(acc[rr][0], acc[rr][1], acc[rr][2], acc[rr][3]);
    for (int j = 0; j < 4; ++j)
      KmatT[((size_t)b * AH + tx * 4 + j) * SLEN + s0 + r] = acc[rr][j];
  }
}

// ---------------------------------------------------------------------------
// Kernel 2: split-K flash attention partials.
// grid = (8 chunks, 32 q-tiles, 4 batches); block = 256 threads.
// Each block: q-tile of 64 rows, key chunk of up to 4 k-tiles (64 keys each).
// Writes unnormalized O partial + per-row (m, l) for the merge pass.
// ---------------------------------------------------------------------------
__global__ __launch_bounds__(256) void flash_partial_kernel(const float* __restrict__ Kmat,
                                                            const float* __restrict__ KmatT,
                                                            float* __restrict__ Opart,
                                                            float* __restrict__ mpart,
                                                            float* __restrict__ lpart) {
  const int chunk = blockIdx.x, qt = blockIdx.y, b = blockIdx.z;
  if (chunk * 4 > qt) return;  // whole block exits uniformly; no barrier hazard

  __shared__ float Qt[64][68];    // Qt[a][r]  (Q transposed)
  __shared__ float KtPt[64][68];  // Kt[a][c] during S; Pt[c][r] during PV
  __shared__ float Vn[64][68];    // Vn[c][a]  (V natural; V == K)

  const int t = threadIdx.x, tx = t & 15, ty = t >> 4;
  const int q0 = qt * 64;
  const int c4 = tx * 4;
  const int ty4 = ty * 4, tx4 = tx * 4;

  // stage Q tile (transposed) from KmatT: rows a, cols r = q0..q0+63
  for (int p = 0; p < 4; ++p) {
    int a = ty + 16 * p;
    *(float4*)&Qt[a][c4] = *(const float4*)&KmatT[((size_t)b * AH + a) * SLEN + q0 + c4];
  }

  float o[4][4] = {{0.f,0.f,0.f,0.f},{0.f,0.f,0.f,0.f},{0.f,0.f,0.f,0.f},{0.f,0.f,0.f,0.f}};
  float m_i[4], l_i[4];
#pragma unroll
  for (int i = 0; i < 4; ++i) { m_i[i] = -INFINITY; l_i[i] = 0.f; }

  const int ktEnd = min(chunk * 4 + 3, qt);
  for (int kt = chunk * 4; kt <= ktEnd; ++kt) {
    const int k0 = kt * 64;
    // stage K tile transposed (Kt[a][c]) from KmatT, and natural (Vn[c][a]) from Kmat
    for (int p = 0; p < 4; ++p) {
      int a = ty + 16 * p;
      *(float4*)&KtPt[a][c4] = *(const float4*)&KmatT[((size_t)b * AH + a) * SLEN + k0 + c4];
    }
    for (int p = 0; p < 4; ++p) {
      int c = ty + 16 * p;
      *(float4*)&Vn[c][c4] = *(const float4*)&Kmat[((size_t)b * SLEN + k0 + c) * AH + c4];
    }
    __syncthreads();

    // S = Q K^T (per-thread 4x4 tile)
    float s[4][4] = {{0.f,0.f,0.f,0.f},{0.f,0.f,0.f,0.f},{0.f,0.f,0.f,0.f},{0.f,0.f,0.f,0.f}};
#pragma unroll 8
    for (int e = 0; e < 64; ++e) {
      float4 qv = *(const float4*)&Qt[e][ty4];
      float4 kv = *(const float4*)&KtPt[e][tx4];
      float qa[4] = {qv.x, qv.y, qv.z, qv.w};
      float ka[4] = {kv.x, kv.y, kv.z, kv.w};
#pragma unroll
      for (int i = 0; i < 4; ++i)
#pragma unroll
        for (int j = 0; j < 4; ++j) s[i][j] += qa[i] * ka[j];
    }
    // scale + faithful mask: strict upper triangle OR exact zero -> -inf
#pragma unroll
    for (int i = 0; i < 4; ++i) {
      int row = q0 + ty4 + i;
#pragma unroll
      for (int j = 0; j < 4; ++j) {
        int col = k0 + tx4 + j;
        float v = s[i][j] * 0.125f;
        if (col > row || v == 0.0f) v = -INFINITY;
        s[i][j] = v;
      }
    }
    __syncthreads();  // everyone done reading KtPt as Kt

    // online softmax (row state replicated across the 16 lanes sharing a row)
#pragma unroll
    for (int i = 0; i < 4; ++i) {
      float rm = fmaxf(fmaxf(s[i][0], s[i][1]), fmaxf(s[i][2], s[i][3]));
      for (int off = 1; off < 16; off <<= 1) rm = fmaxf(rm, __shfl_xor(rm, off, 16));
      float mn = fmaxf(m_i[i], rm);
      float alpha = (m_i[i] == -INFINITY) ? 0.f : __expf(m_i[i] - mn);
      float p[4], rs = 0.f;
#pragma unroll
      for (int j = 0; j < 4; ++j) {
        p[j] = (s[i][j] == -INFINITY) ? 0.f : __expf(s[i][j] - mn);
        rs += p[j];
      }
      for (int off = 1; off < 16; off <<= 1) rs += __shfl_xor(rs, off, 16);
      l_i[i] = l_i[i] * alpha + rs;
      m_i[i] = mn;
#pragma unroll
      for (int j = 0; j < 4; ++j) o[i][j] *= alpha;
      // write P transposed: Pt[c][r]
#pragma unroll
      for (int j = 0; j < 4; ++j) KtPt[tx4 + j][ty4 + i] = p[j];
    }
    __syncthreads();  // Pt visible to all waves

    // O += P V
#pragma unroll 8
    for (int c = 0; c < 64; ++c) {
      float4 pv = *(const float4*)&KtPt[c][ty4];
      float4 vv = *(const float4*)&Vn[c][tx4];
      float pa[4] = {pv.x, pv.y, pv.z, pv.w};
      float va[4] = {vv.x, vv.y, vv.z, vv.w};
#pragma unroll
      for (int i = 0; i < 4; ++i)
#pragma unroll
        for (int j = 0; j < 4; ++j) o[i][j] += pa[i] * va[j];
    }
    __syncthreads();  // before next staging overwrites KtPt/Vn
  }

  // write partials
  const size_t slot = (size_t)(b * 32 + qt) * 8 + chunk;
  float* Ob = Opart + slot * 4096;
#pragma unroll
  for (int i = 0; i < 4; ++i)
    *(float4*)&Ob[(size_t)(ty4 + i) * 64 + tx4] =
        make_float4(o[i][0], o[i][1], o[i][2], o[i][3]);
  if (tx == 0) {
#pragma unroll
    for (int i = 0; i < 4; ++i) {
      mpart[slot * 64 + ty4 + i] = m_i[i];
      lpart[slot * 64 + ty4 + i] = l_i[i];
    }
  }
}

// ---------------------------------------------------------------------------
// Kernel 3: merge split-K partials (log-sum-exp combine) and write output.
// grid = (32 q-tiles, 4 batches); 256 threads; thread -> (row r=t/4, 16 a's).
// ---------------------------------------------------------------------------
__global__ __launch_bounds__(256) void merge_kernel(const float* __restrict__ Opart,
                                                    const float* __restrict__ mpart,
                                                    const float* __restrict__ lpart,
                                                    float* __restrict__ out) {
  const int qt = blockIdx.x, b = blockIdx.y;
  const int t = threadIdx.x;
  const int r = t >> 2;
  const int a0 = (t & 3) * 16;
  const int nch = qt / 4 + 1;
  const size_t base_slot = (size_t)(b * 32 + qt) * 8;

  float M = -INFINITY;
  for (int c = 0; c < nch; ++c) M = fmaxf(M, mpart[(base_slot + c) * 64 + r]);

  float L = 0.f;
  float acc[16];
#pragma unroll
  for (int k = 0; k < 16; ++k) acc[k] = 0.f;

  for (int c = 0; c < nch; ++c) {
    float mj = mpart[(base_slot + c) * 64 + r];
    float lj = lpart[(base_slot + c) * 64 + r];
    float w = (mj == -INFINITY) ? 0.f : __expf(mj - M);
    L += lj * w;
    const float* Ob = Opart + (base_slot + c) * 4096 + (size_t)r * 64 + a0;
#pragma unroll
    for (int k = 0; k < 16; k += 4) {
      float4 v = *(const float4*)&Ob[k];
      acc[k + 0] += v.x * w; acc[k + 1] += v.y * w;
      acc[k + 2] += v.z * w; acc[k + 3] += v.w * w;
    }
  }
  float inv = 1.0f / L;
  float* op = &out[((size_t)b * SLEN + qt * 64 + r) * AH + a0];
#pragma unroll
  for (int k = 0; k < 16; k += 4)
    *(float4*)&op[k] = make_float4(acc[k] * inv, acc[k + 1] * inv,
                                   acc[k + 2] * inv, acc[k + 3] * inv);
}

// ---------------------------------------------------------------------------
// Workspace layout (floats):
//   WkT    [0,       65536)
//   Kmat   [65536,   590  -> 65536 + 524288)
//   KmatT  [589824,  +524288)
//   Opart  [1114112, +4194304)   (1024 slots x 64x64)
//   mpart  [5308416, +65536)
//   lpart  [5373952, +65536)     total ~21.8 MB
// ---------------------------------------------------------------------------
extern "C" void kernel_launch(void* const* d_in, const int* in_sizes, int n_in,
                              void* d_out, int out_size, void* d_ws, size_t ws_size,
                              hipStream_t stream) {
  const float* emb = (const float*)d_in[0];
  const float* Wk  = (const float*)d_in[1];
  float* out = (float*)d_out;
  float* ws  = (float*)d_ws;

  float* WkT   = ws;
  float* Kmat  = ws + 65536;
  float* KmatT = ws + 65536 + 524288;
  float* Opart = ws + 1114112;
  float* mpart = ws + 5308416;
  float* lpart = ws + 5373952;

  wk_transpose_kernel<<<dim3(256), dim3(256), 0, stream>>>(Wk, WkT);
  gemm_k_kernel<<<dim3(256), dim3(256), 0, stream>>>(emb, WkT, Kmat, KmatT);
  flash_partial_kernel<<<dim3(8, 32, 4), dim3(256), 0, stream>>>(Kmat, KmatT, Opart, mpart, lpart);
  merge_kernel<<<dim3(32, 4), dim3(256), 0, stream>>>(Opart, mpart, lpart, out);
}

// Round 2
// 146.655 us; speedup vs baseline: 1.2568x; 1.2568x over previous
//
#include <hip/hip_runtime.h>
#include <math.h>

// Problem constants (B=4, S=2048, E=1024, A=64)
#define BATCH 4
#define SLEN  2048
#define EMB   1024
#define AH    64

typedef __attribute__((ext_vector_type(8))) short bf16x8;
typedef __attribute__((ext_vector_type(4))) float f32x4;

__device__ __forceinline__ short f2bf(float x) {
  union { float f; unsigned u; } v; v.f = x;
  unsigned r = v.u + 0x7fffu + ((v.u >> 16) & 1u);
  return (short)(r >> 16);
}
__device__ __forceinline__ float bf2f(short h) {
  union { unsigned u; float f; } v; v.u = ((unsigned)(unsigned short)h) << 16;
  return v.f;
}

// ---------------------------------------------------------------------------
// Kernel 0: pack Wk [64,1024] fp32 into MFMA B-fragment order, split bf16.
// Bpk layout: [h(2)][kc(32)][nt(4)][lane(64)][j(8)] bf16.
// B[k][n] = Wk[n][k]; lane holds n = nt*16 + (lane&15), k = kc*32+(lane>>4)*8+j.
// ---------------------------------------------------------------------------
__global__ __launch_bounds__(256) void prep_wk_kernel(const float* __restrict__ Wk,
                                                      short* __restrict__ Bpk) {
  int tg = blockIdx.x * 256 + threadIdx.x;  // 8192 = 32kc * 4nt * 64lane
  int kc = tg >> 8, rem = tg & 255, nt = rem >> 6, lane = rem & 63;
  int n = nt * 16 + (lane & 15);
  int k = kc * 32 + (lane >> 4) * 8;
  const float* src = Wk + (size_t)n * EMB + k;
  float4 a0 = *(const float4*)src;
  float4 a1 = *(const float4*)(src + 4);
  float x[8] = {a0.x, a0.y, a0.z, a0.w, a1.x, a1.y, a1.z, a1.w};
  bf16x8 hi, lo;
#pragma unroll
  for (int j = 0; j < 8; ++j) {
    short h = f2bf(x[j]);
    hi[j] = h;
    lo[j] = f2bf(x[j] - bf2f(h));
  }
  short* dst = Bpk + ((size_t)(kc * 4 + nt) * 64 + lane) * 8;
  *(bf16x8*)dst = hi;
  *(bf16x8*)(dst + 65536) = lo;  // lo plane: 32*4*64*8 = 65536 elements
}

// ---------------------------------------------------------------------------
// Kernel 1: K = emb @ Wk^T via split-bf16 MFMA (fp32-accurate: hh+hl+lh).
// grid 512 x 256 threads; block = 16 rows x 64 cols; wave w owns n-tile w.
// No LDS, no barriers: A fragments read straight from emb (coalesced),
// B fragments from pre-packed Bpk (L2-resident).
// Outputs: Khi/Klo [8192][64] bf16 (natural), KThi [4][64][2048] bf16.
// ---------------------------------------------------------------------------
__global__ __launch_bounds__(256) void gemm_k_kernel(const float* __restrict__ emb,
                                                     const short* __restrict__ Bpk,
                                                     short* __restrict__ Khi,
                                                     short* __restrict__ Klo,
                                                     short* __restrict__ KThi) {
  const int t = threadIdx.x;
  const int w = t >> 6, l = t & 63, lm = l & 15, quad = l >> 4;
  const int row0 = blockIdx.x * 16;
  const int nt = w;

  f32x4 acc = {0.f, 0.f, 0.f, 0.f};
  const float* arow = emb + (size_t)(row0 + lm) * EMB + quad * 8;

#pragma unroll 4
  for (int kc = 0; kc < 32; ++kc) {
    float4 a0 = *(const float4*)(arow + kc * 32);
    float4 a1 = *(const float4*)(arow + kc * 32 + 4);
    float x[8] = {a0.x, a0.y, a0.z, a0.w, a1.x, a1.y, a1.z, a1.w};
    bf16x8 ahi, alo;
#pragma unroll
    for (int j = 0; j < 8; ++j) {
      short h = f2bf(x[j]);
      ahi[j] = h;
      alo[j] = f2bf(x[j] - bf2f(h));
    }
    const short* bp = Bpk + ((size_t)(kc * 4 + nt) * 64 + l) * 8;
    bf16x8 bhi = *(const bf16x8*)bp;
    bf16x8 blo = *(const bf16x8*)(bp + 65536);
    acc = __builtin_amdgcn_mfma_f32_16x16x32_bf16(ahi, bhi, acc, 0, 0, 0);
    acc = __builtin_amdgcn_mfma_f32_16x16x32_bf16(ahi, blo, acc, 0, 0, 0);
    acc = __builtin_amdgcn_mfma_f32_16x16x32_bf16(alo, bhi, acc, 0, 0, 0);
  }

  // epilogue: C layout col=lm, row=quad*4+r
  const int b = row0 >> 11, s0 = row0 & 2047;
  short hi4[4];
#pragma unroll
  for (int r = 0; r < 4; ++r) {
    float v = acc[r];
    short h = f2bf(v);
    short lo = f2bf(v - bf2f(h));
    hi4[r] = h;
    size_t idx = (size_t)(row0 + quad * 4 + r) * AH + nt * 16 + lm;
    Khi[idx] = h;
    Klo[idx] = lo;
  }
  // KT: fixed col a, 4 consecutive s -> one 8B store
  size_t kt_idx = ((size_t)b * AH + nt * 16 + lm) * SLEN + s0 + quad * 4;
  *(short4*)&KThi[kt_idx] = make_short4(hi4[0], hi4[1], hi4[2], hi4[3]);
}

// ---------------------------------------------------------------------------
// Kernel 2: split-K flash attention partials, MFMA, zero barriers.
// grid (8 chunks, 32 q-tiles, 4 batches) x 256; wave w = 16 q-rows, private.
// QK^T: split-bf16 (3 MFMAs / 32-k chunk); PV: P bf16 x V hi.
// ---------------------------------------------------------------------------
__global__ __launch_bounds__(256) void flash_partial_kernel(const short* __restrict__ Khi,
                                                            const short* __restrict__ Klo,
                                                            const short* __restrict__ KThi,
                                                            float* __restrict__ Opart,
                                                            float* __restrict__ mpart,
                                                            float* __restrict__ lpart) {
  const int chunk = blockIdx.x, qt = blockIdx.y, b = blockIdx.z;
  if (chunk * 4 > qt) return;

  __shared__ short Plds[4][16][88];  // per-wave private P buffer (row stride 176B: 16B-aligned, 2-way banks)

  const int t = threadIdx.x;
  const int w = t >> 6, l = t & 63, lm = l & 15, quad = l >> 4;
  const int qr0 = qt * 64 + w * 16;

  // Q fragments (A-operand): 16B contiguous per lane from K natural layout
  const size_t qbase = ((size_t)b * SLEN + qr0 + lm) * AH + quad * 8;
  const bf16x8 qhi0 = *(const bf16x8*)(Khi + qbase);
  const bf16x8 qhi1 = *(const bf16x8*)(Khi + qbase + 32);
  const bf16x8 qlo0 = *(const bf16x8*)(Klo + qbase);
  const bf16x8 qlo1 = *(const bf16x8*)(Klo + qbase + 32);

  f32x4 o[4];
  float m_i[4], l_i[4];
#pragma unroll
  for (int r = 0; r < 4; ++r) {
    o[r] = (f32x4){0.f, 0.f, 0.f, 0.f};
    m_i[r] = -INFINITY;
    l_i[r] = 0.f;
  }

  const int ktEnd = min(chunk * 4 + 3, qt);
  for (int kt = chunk * 4; kt <= ktEnd; ++kt) {
    const int k0 = kt * 64;

    // ---- S = Q K^T (split bf16: hh + hl + lh) ----
    f32x4 sc[4];
#pragma unroll
    for (int nt = 0; nt < 4; ++nt) {
      sc[nt] = (f32x4){0.f, 0.f, 0.f, 0.f};
      const size_t kb = ((size_t)b * SLEN + k0 + nt * 16 + lm) * AH + quad * 8;
      bf16x8 bh0 = *(const bf16x8*)(Khi + kb);
      bf16x8 bl0 = *(const bf16x8*)(Klo + kb);
      bf16x8 bh1 = *(const bf16x8*)(Khi + kb + 32);
      bf16x8 bl1 = *(const bf16x8*)(Klo + kb + 32);
      sc[nt] = __builtin_amdgcn_mfma_f32_16x16x32_bf16(qhi0, bh0, sc[nt], 0, 0, 0);
      sc[nt] = __builtin_amdgcn_mfma_f32_16x16x32_bf16(qhi0, bl0, sc[nt], 0, 0, 0);
      sc[nt] = __builtin_amdgcn_mfma_f32_16x16x32_bf16(qlo0, bh0, sc[nt], 0, 0, 0);
      sc[nt] = __builtin_amdgcn_mfma_f32_16x16x32_bf16(qhi1, bh1, sc[nt], 0, 0, 0);
      sc[nt] = __builtin_amdgcn_mfma_f32_16x16x32_bf16(qhi1, bl1, sc[nt], 0, 0, 0);
      sc[nt] = __builtin_amdgcn_mfma_f32_16x16x32_bf16(qlo1, bh1, sc[nt], 0, 0, 0);
    }

    // ---- mask + online softmax (C layout: row=quad*4+r, col=nt*16+lm) ----
    float sv[4][4];
    float rm[4] = {-INFINITY, -INFINITY, -INFINITY, -INFINITY};
#pragma unroll
    for (int nt = 0; nt < 4; ++nt) {
      const int col = k0 + nt * 16 + lm;
#pragma unroll
      for (int r = 0; r < 4; ++r) {
        const int row = qr0 + quad * 4 + r;
        float v = sc[nt][r] * 0.125f;
        if (col > row || v == 0.0f) v = -INFINITY;
        sv[nt][r] = v;
        rm[r] = fmaxf(rm[r], v);
      }
    }
#pragma unroll
    for (int r = 0; r < 4; ++r) {
      for (int off = 1; off < 16; off <<= 1) rm[r] = fmaxf(rm[r], __shfl_xor(rm[r], off, 16));
      float mn = fmaxf(m_i[r], rm[r]);
      float alpha = (m_i[r] == -INFINITY) ? 0.f : __expf(m_i[r] - mn);
      m_i[r] = mn;
      l_i[r] *= alpha;
#pragma unroll
      for (int nt = 0; nt < 4; ++nt) o[nt][r] *= alpha;
    }
    float pv[4][4], rs[4] = {0.f, 0.f, 0.f, 0.f};
#pragma unroll
    for (int nt = 0; nt < 4; ++nt)
#pragma unroll
      for (int r = 0; r < 4; ++r) {
        float p = (sv[nt][r] == -INFINITY) ? 0.f : __expf(sv[nt][r] - m_i[r]);
        pv[nt][r] = p;
        rs[r] += p;
      }
#pragma unroll
    for (int r = 0; r < 4; ++r) {
      for (int off = 1; off < 16; off <<= 1) rs[r] += __shfl_xor(rs[r], off, 16);
      l_i[r] += rs[r];
    }

    // ---- P -> LDS (C layout -> A-operand layout), per-wave private ----
#pragma unroll
    for (int nt = 0; nt < 4; ++nt)
#pragma unroll
      for (int r = 0; r < 4; ++r)
        Plds[w][quad * 4 + r][nt * 16 + lm] = f2bf(pv[nt][r]);

    // ---- O += P V  (V = K; B-frags from KThi, 16B contiguous per lane) ----
#pragma unroll
    for (int kc2 = 0; kc2 < 2; ++kc2) {
      bf16x8 pf = *(const bf16x8*)&Plds[w][lm][kc2 * 32 + quad * 8];
#pragma unroll
      for (int nt = 0; nt < 4; ++nt) {
        const size_t vb = ((size_t)b * AH + nt * 16 + lm) * SLEN + k0 + kc2 * 32 + quad * 8;
        bf16x8 vf = *(const bf16x8*)(KThi + vb);
        o[nt] = __builtin_amdgcn_mfma_f32_16x16x32_bf16(pf, vf, o[nt], 0, 0, 0);
      }
    }
  }

  // ---- write partials (same layout as merge expects) ----
  const size_t slot = (size_t)(b * 32 + qt) * 8 + chunk;
  float* Ob = Opart + slot * 4096;
#pragma unroll
  for (int nt = 0; nt < 4; ++nt)
#pragma unroll
    for (int r = 0; r < 4; ++r)
      Ob[(size_t)(w * 16 + quad * 4 + r) * 64 + nt * 16 + lm] = o[nt][r];
  if (lm == 0) {
#pragma unroll
    for (int r = 0; r < 4; ++r) {
      mpart[slot * 64 + w * 16 + quad * 4 + r] = m_i[r];
      lpart[slot * 64 + w * 16 + quad * 4 + r] = l_i[r];
    }
  }
}

// ---------------------------------------------------------------------------
// Kernel 3: merge split-K partials (log-sum-exp combine) and write output.
// ---------------------------------------------------------------------------
__global__ __launch_bounds__(256) void merge_kernel(const float* __restrict__ Opart,
                                                    const float* __restrict__ mpart,
                                                    const float* __restrict__ lpart,
                                                    float* __restrict__ out) {
  const int qt = blockIdx.x, b = blockIdx.y;
  const int t = threadIdx.x;
  const int r = t >> 2;
  const int a0 = (t & 3) * 16;
  const int nch = qt / 4 + 1;
  const size_t base_slot = (size_t)(b * 32 + qt) * 8;

  float M = -INFINITY;
  for (int c = 0; c < nch; ++c) M = fmaxf(M, mpart[(base_slot + c) * 64 + r]);

  float L = 0.f;
  float acc[16];
#pragma unroll
  for (int k = 0; k < 16; ++k) acc[k] = 0.f;

  for (int c = 0; c < nch; ++c) {
    float mj = mpart[(base_slot + c) * 64 + r];
    float lj = lpart[(base_slot + c) * 64 + r];
    float wgt = (mj == -INFINITY) ? 0.f : __expf(mj - M);
    L += lj * wgt;
    const float* Ob = Opart + (base_slot + c) * 4096 + (size_t)r * 64 + a0;
#pragma unroll
    for (int k = 0; k < 16; k += 4) {
      float4 v = *(const float4*)&Ob[k];
      acc[k + 0] += v.x * wgt; acc[k + 1] += v.y * wgt;
      acc[k + 2] += v.z * wgt; acc[k + 3] += v.w * wgt;
    }
  }
  float inv = 1.0f / L;
  float* op = &out[((size_t)b * SLEN + qt * 64 + r) * AH + a0];
#pragma unroll
  for (int k = 0; k < 16; k += 4)
    *(float4*)&op[k] = make_float4(acc[k] * inv, acc[k + 1] * inv,
                                   acc[k + 2] * inv, acc[k + 3] * inv);
}

// ---------------------------------------------------------------------------
// Workspace layout (bytes):
//   Bpk    [0,        262144)    bf16 packed Wk fragments (hi+lo)
//   Khi    [262144,   1310720)   8192x64 bf16
//   Klo    [1310720,  2359296)
//   KThi   [2359296,  3407872)   4x64x2048 bf16
//   Opart  [3407872,  20185088)  1024 slots x 64x64 fp32
//   mpart  [20185088, 20447232)
//   lpart  [20447232, 20709376)  total ~19.8 MB
// ---------------------------------------------------------------------------
extern "C" void kernel_launch(void* const* d_in, const int* in_sizes, int n_in,
                              void* d_out, int out_size, void* d_ws, size_t ws_size,
                              hipStream_t stream) {
  const float* emb = (const float*)d_in[0];
  const float* Wk  = (const float*)d_in[1];
  float* out = (float*)d_out;
  char* ws = (char*)d_ws;

  short* Bpk   = (short*)(ws);
  short* Khi   = (short*)(ws + 262144);
  short* Klo   = (short*)(ws + 1310720);
  short* KThi  = (short*)(ws + 2359296);
  float* Opart = (float*)(ws + 3407872);
  float* mpart = (float*)(ws + 20185088);
  float* lpart = (float*)(ws + 20447232);

  prep_wk_kernel<<<dim3(32), dim3(256), 0, stream>>>(Wk, Bpk);
  gemm_k_kernel<<<dim3(512), dim3(256), 0, stream>>>(emb, Bpk, Khi, Klo, KThi);
  flash_partial_kernel<<<dim3(8, 32, 4), dim3(256), 0, stream>>>(Khi, Klo, KThi, Opart, mpart, lpart);
  merge_kernel<<<dim3(32, 4), dim3(256), 0, stream>>>(Opart, mpart, lpart, out);
}